// Round 1
// 79.132 us; speedup vs baseline: 1.0031x; 1.0031x over previous
//
#include <hip/hip_runtime.h>

// Problem constants (from reference): B=4, N=256, FE=8, CIN=16, COUT=16, H=64
#define B_    4
#define N_    256
#define FE_   8
#define CIN_  16
#define COUT_ 16
#define H_    64
#define JG_   4   // j-columns per block

// R5 restructure: one block per (b, 4-consecutive-j group).
// Rationale (counter model): old layout gathered 32B slices of 128B edge
// lines (33.5MB L2 reads) and re-read the full 64KB W2 per (b,j) block
// (64MB L2 reads) -> ~2.8us L2-bound floor ~= the 2.6us fp32-FMA floor.
// 4-column blocks make the edge stage perfectly 128B-coalesced (each line
// read exactly once chip-wide: 8.4MB exact), cut W2 L2 traffic 4x, and
// make output stores full 256B lines. Occupancy unchanged: 256 blocks x
// 16 waves = 16 waves/CU (1 block/CU).
//
// out[b,j,d] = sum_c node[b,j,c] * ( Wsum[b,j,c,d] + root[c,d] )
// Wsum[b,j]  = Hsum[b,j,:] @ W2 + N*b2
// Hsum[b,j,h]= sum_i relu( edge[b,i,j,:] @ W1 + b1 )[h]

__global__ __launch_bounds__(1024) void nnconv_fused4(
    const float* __restrict__ node_attr,  // [B,N,CIN]
    const float* __restrict__ edge_adj,   // [B,N,N,FE]
    const float* __restrict__ W1,         // [FE,H]
    const float* __restrict__ b1,         // [H]
    const float* __restrict__ W2,         // [H, CIN*COUT]
    const float* __restrict__ b2,         // [CIN*COUT]
    const float* __restrict__ root,       // [CIN,COUT]
    float* __restrict__ out)              // [B,N,COUT]
{
    const int blk = blockIdx.x;           // 0..255 (== CU count, no swizzle needed:
    const int b   = blk >> 6;             //  every edge line is block-exclusive now)
    const int j0  = (blk & 63) << 2;      // 0,4,...,252
    const int t    = threadIdx.x;         // 0..1023
    const int lane = t & 63;              // h index in main loop
    const int w    = t >> 6;              // wave 0..15

    __shared__ float e_s[N_][JG_ * FE_];        // [256][32] = 32 KB, 128B rows
    __shared__ float hpart[JG_][4][H_];         // 4 KB
    __shared__ float Hsum[JG_][H_];             // 1 KB
    __shared__ float contrib[JG_][CIN_][COUT_]; // 4 KB

    // ---- stage edge rows: 2048 float4 = 32 KB. q = i*8 + f4; the 8 float4
    // of row i (cols j0..j0+3, f=0..7) are CONTIGUOUS in global memory:
    // float4 idx = (b*256+i)*512 + j0*2 + f4. 8 consecutive threads fetch
    // one full 128B line. Thread t loads q=t and q=t+1024.
    {
        const float4* eg = (const float4*)edge_adj;
        float4* es4 = (float4*)(&e_s[0][0]);
        const int q0 = t;
        const int q1 = t + 1024;
        const size_t base = (size_t)b * (N_ * 512) + j0 * 2;
        float4 v0 = eg[base + (size_t)(q0 >> 3) * 512 + (q0 & 7)];
        float4 v1 = eg[base + (size_t)(q1 >> 3) * 512 + (q1 & 7)];
        es4[q0] = v0;
        es4[q1] = v1;
    }

    // W1 column for h=lane: 256B-coalesced per f, lives in 9 VGPRs
    float w1r[FE_];
    #pragma unroll
    for (int f = 0; f < FE_; ++f) w1r[f] = W1[f * H_ + lane];
    const float b1r = b1[lane];

    __syncthreads();

    // ---- main loop: wave w -> column g = w&3, i in [(w>>2)*64, +64).
    // e_s reads are wave-uniform -> LDS broadcast (conflict-free).
    // Two independent accumulator chains (even/odd i) for ILP.
    const int g  = w & 3;
    const int i0 = (w >> 2) << 6;
    float accA = 0.f, accB = 0.f;
    #pragma unroll 8
    for (int k = 0; k < 64; k += 2) {
        const float4* ev0 = (const float4*)(&e_s[i0 + k][g * FE_]);
        const float4* ev1 = (const float4*)(&e_s[i0 + k + 1][g * FE_]);
        const float4 ea = ev0[0], eb = ev0[1];
        const float4 fa = ev1[0], fb = ev1[1];
        float v0 = b1r, v1 = b1r;
        v0 = fmaf(ea.x, w1r[0], v0);  v1 = fmaf(fa.x, w1r[0], v1);
        v0 = fmaf(ea.y, w1r[1], v0);  v1 = fmaf(fa.y, w1r[1], v1);
        v0 = fmaf(ea.z, w1r[2], v0);  v1 = fmaf(fa.z, w1r[2], v1);
        v0 = fmaf(ea.w, w1r[3], v0);  v1 = fmaf(fa.w, w1r[3], v1);
        v0 = fmaf(eb.x, w1r[4], v0);  v1 = fmaf(fb.x, w1r[4], v1);
        v0 = fmaf(eb.y, w1r[5], v0);  v1 = fmaf(fb.y, w1r[5], v1);
        v0 = fmaf(eb.z, w1r[6], v0);  v1 = fmaf(fb.z, w1r[6], v1);
        v0 = fmaf(eb.w, w1r[7], v0);  v1 = fmaf(fb.w, w1r[7], v1);
        accA += fmaxf(v0, 0.f);
        accB += fmaxf(v1, 0.f);
    }
    hpart[g][w >> 2][lane] = accA + accB;
    __syncthreads();

    if (t < JG_ * H_) {                   // 256 threads reduce 4 i-quarters
        const int gg = t >> 6, hh = t & 63;
        Hsum[gg][hh] = hpart[gg][0][hh] + hpart[gg][1][hh]
                     + hpart[gg][2][hh] + hpart[gg][3][hh];
    }
    __syncthreads();

    // ---- step 2: Wsum. Group g2 = t>>8 (4 waves) handles column j0+g2,
    // element td = c*COUT+d. W2 rows read 256B-coalesced per wave; one W2
    // stream now serves 4 columns (L2 traffic 64MB -> 16MB chip-wide).
    const int g2 = t >> 8;
    const int td = t & 255;
    float s0 = 0.f, s1 = 0.f, s2 = 0.f, s3 = 0.f;
    #pragma unroll
    for (int hq = 0; hq < 16; ++hq) {
        const float4 hv = *(const float4*)(&Hsum[g2][hq * 4]);
        s0 = fmaf(hv.x, W2[(hq * 4 + 0) * 256 + td], s0);
        s1 = fmaf(hv.y, W2[(hq * 4 + 1) * 256 + td], s1);
        s2 = fmaf(hv.z, W2[(hq * 4 + 2) * 256 + td], s2);
        s3 = fmaf(hv.w, W2[(hq * 4 + 3) * 256 + td], s3);
    }
    const float ws = (float)N_ * b2[td] + ((s0 + s1) + (s2 + s3));

    // ---- step 3: out[d] = sum_c node[c] * (ws[c,d] + root[c,d])
    const int c = td >> 4;
    const int d = td & 15;
    const float nodec = node_attr[((size_t)b * N_ + (j0 + g2)) * CIN_ + c];
    contrib[g2][c][d] = nodec * (ws + root[td]);
    __syncthreads();

    if (t < JG_ * COUT_) {                // 64 threads -> 256B contiguous store
        const int gg = t >> 4, dd = t & 15;
        float o = 0.f;
        #pragma unroll
        for (int cc = 0; cc < CIN_; ++cc) o += contrib[gg][cc][dd];
        out[((size_t)b * N_ + (j0 + gg)) * COUT_ + dd] = o;
    }
}

extern "C" void kernel_launch(void* const* d_in, const int* in_sizes, int n_in,
                              void* d_out, int out_size, void* d_ws, size_t ws_size,
                              hipStream_t stream) {
    const float* node_attr = (const float*)d_in[0];  // [B,N,CIN]
    const float* edge_adj  = (const float*)d_in[1];  // [B,N,N,FE]
    const float* W1        = (const float*)d_in[2];  // [FE,H]
    const float* b1        = (const float*)d_in[3];  // [H]
    const float* W2        = (const float*)d_in[4];  // [H,CIN*COUT]
    const float* b2        = (const float*)d_in[5];  // [CIN*COUT]
    const float* root      = (const float*)d_in[6];  // [CIN,COUT]
    float* out = (float*)d_out;                      // [B,N,COUT]

    nnconv_fused4<<<dim3(B_ * (N_ / JG_)), dim3(1024), 0, stream>>>(
        node_attr, edge_adj, W1, b1, W2, b2, root, out);
}